// Round 11
// baseline (665.170 us; speedup 1.0000x reference)
//
#include <hip/hip_runtime.h>
#include <cstdint>
#include <cstddef>

// Problem shape (fixed by setup_inputs)
#define NND   10000     // nodes per graph
#define NED   160000    // edges per graph
#define NB    8         // batch
#define NF    256       // in features
#define NHID  64        // hidden per head
#define HEADS 8
#define F1    512       // HEADS*NHID
#define NCLS  64        // out classes

#define NSH   8         // bucket shift: 256 nodes per bucket
#define NBUCK 40        // ceil(NND/256)
#define CHUNK 4096      // edges per scat_a block

#define ALPHA_SLOPE 0.2f
#define OUT_SLOPE   0.01f
#define EPS         1e-16f

typedef unsigned short u16;
typedef short short8 __attribute__((ext_vector_type(8)));
typedef float f32x4 __attribute__((ext_vector_type(4)));

// ---------------- ws layout (byte offsets, 16B-aligned) ----------------
static const size_t B_WCHI = 0;                      // u16 frag-order [256][64][8]
static const size_t B_WCLO = 262144;
static const size_t B_WOHI = 524288;                 // u16 [64][512]
static const size_t B_WOLO = 589824;
static const size_t B_AS1  = 655360;                 // f32 [8][N][8]
static const size_t B_AD1  = 3215360;
static const size_t B_AS2  = 5775360;                // f32 [8][N]
static const size_t B_AD2  = 6095360;
static const size_t B_CNT  = 6415360;                // int [8][N]
static const size_t B_BCUR = 6735360;                // int [8][NBUCK] (pad to 4096)
static const size_t B_ROWS = 6739456;                // int [8][N+1]
static const size_t B_TMP  = 7059520;                // u32 [8][E] packed (s<<16|d)
static const size_t B_DST  = 12179520;               // u16 [8][E]
static const size_t B_SCR  = 14739520;               // Z slots
// per-z slot layout in u16 units (ZSTRU total):
//   off 0:          xchi [N][F1]
//   off 5,120,000:  xclo [N][F1]
//   off 10,240,000: h1   [HEADS][N][64]  (head-major!)
//   off 15,360,000: h2   [N][NCLS]
#define ZSTRU 16000000ull
static const size_t S_PERZ = 2 * ZSTRU;              // bytes = 32,000,000

// ---------------- helpers ----------------
__device__ __forceinline__ u16 f32_to_bf16_rn(float f) {
  uint32_t u = __float_as_uint(f);
  uint32_t r = u + 0x7fffu + ((u >> 16) & 1u);
  return (u16)(r >> 16);
}
__device__ __forceinline__ float bf16_to_f32(u16 s) {
  return __uint_as_float((uint32_t)s << 16);
}
__device__ __forceinline__ void split1(float v, u16& h, u16& l) {
  h = f32_to_bf16_rn(v);
  float r = v - bf16_to_f32(h);
  l = f32_to_bf16_rn(r);
}

// ---------------- weight prep ----------------
// W_heads -> MFMA-fragment-order: frag = ((by*8 + t)*4 + w)*4 + nj ; per frag
// 64 lanes x 8 u16.  Element (lane, j): n = by*256+w*64+nj*16+(lane&15),
// k = t*32 + (lane>>4)*8 + j.  One wave's fragment load = 1KB contiguous.
__global__ __launch_bounds__(256) void k_wsplit1(const float* __restrict__ Whd,
                                                 u16* __restrict__ hi,
                                                 u16* __restrict__ lo) {
  int t = blockIdx.x * 256 + threadIdx.x;   // 16384 threads
  int lane = t & 63;
  int frag = t >> 6;                        // 0..255
  int nj = frag & 3;
  int w  = (frag >> 2) & 3;
  int ts = (frag >> 4) & 7;
  int by = frag >> 7;
  int lm = lane & 15, lkg = lane >> 4;
  int n = by * 256 + w * 64 + nj * 16 + lm;
  int h = n >> 6, nc = n & 63;
  u16 hv[8], lv[8];
#pragma unroll
  for (int j = 0; j < 8; ++j) {
    int k = ts * 32 + lkg * 8 + j;
    split1(Whd[h * (NF * NHID) + k * NHID + nc], hv[j], lv[j]);
  }
  size_t o = (size_t)t * 8;
  *(ushort4*)(hi + o) = make_ushort4(hv[0], hv[1], hv[2], hv[3]);
  *(ushort4*)(hi + o + 4) = make_ushort4(hv[4], hv[5], hv[6], hv[7]);
  *(ushort4*)(lo + o) = make_ushort4(lv[0], lv[1], lv[2], lv[3]);
  *(ushort4*)(lo + o + 4) = make_ushort4(lv[4], lv[5], lv[6], lv[7]);
}
__global__ __launch_bounds__(256) void k_wsplit2(const float* __restrict__ Wo,
                                                 u16* __restrict__ hi,
                                                 u16* __restrict__ lo) {
  int idx = blockIdx.x * 256 + threadIdx.x;   // 64*512
  int n = idx >> 9, k = idx & 511;
  float v = Wo[k * NCLS + n];
  u16 h, l; split1(v, h, l);
  hi[idx] = h; lo[idx] = l;
}

// ---------------- layer-1 GEMM: BM=64, BN=256; A in LDS, B frag from L2 ------
// 1-D grid, z = blockIdx.x & (Z-1) -> batch z pinned to XCD z (when Z=8).
// Wave w owns cols [by*256 + w*64, +64) == head hb = by*4+w.
// h1 written HEAD-MAJOR: C[hb][gm][64].
__global__ __launch_bounds__(256) void k_gemm1(
    const float* __restrict__ x,
    const u16* __restrict__ Bfh, const u16* __restrict__ Bfl,
    u16* __restrict__ h1_s,
    const float* __restrict__ avec,
    float* __restrict__ as_g, float* __restrict__ ad_g,
    int base_b, int zsh) {
  __shared__ u16 As_hi[64][40];
  __shared__ u16 As_lo[64][40];

  const int zmask = (1 << zsh) - 1;
  const int z = blockIdx.x & zmask;
  const int wg = blockIdx.x >> zsh;        // 0..313
  const int b = base_b + z;
  const float* A = x + (size_t)b * NND * NF;
  u16* C = h1_s + (size_t)z * ZSTRU;
  float* as_ = as_g + (size_t)b * NND * 8;
  float* ad_ = ad_g + (size_t)b * NND * 8;

  const int m0 = (wg >> 1) * 64;
  const int by = wg & 1;

  const int tid = threadIdx.x;
  const int lane = tid & 63;
  const int w = tid >> 6;
  const int lm = lane & 15;
  const int lkg = lane >> 4;
  const int hb = by * 4 + w;

  f32x4 acc[4][4];
#pragma unroll
  for (int mi = 0; mi < 4; ++mi)
#pragma unroll
    for (int nj = 0; nj < 4; ++nj) acc[mi][nj] = 0.f;

  for (int t = 0; t < 8; ++t) {
    const int kk = t * 32;
    __syncthreads();
    // stage A: 64 rows x 32 f32, fused split; 512 float4 units
#pragma unroll
    for (int u = 0; u < 2; ++u) {
      int e = u * 256 + tid;
      int rr = e >> 3, kf = (e & 7) * 4;
      int gm = m0 + rr;
      float4 v = make_float4(0.f, 0.f, 0.f, 0.f);
      if (gm < NND) v = *(const float4*)(A + (size_t)gm * NF + kk + kf);
      ushort4 hv, lv;
      split1(v.x, hv.x, lv.x); split1(v.y, hv.y, lv.y);
      split1(v.z, hv.z, lv.z); split1(v.w, hv.w, lv.w);
      *(ushort4*)&As_hi[rr][kf] = hv;
      *(ushort4*)&As_lo[rr][kf] = lv;
    }
    // B fragments straight from global (L2-hot, coalesced 1KB per load)
    short8 bh[4], bl[4];
    {
      size_t fb = (((size_t)(by * 8 + t) * 4 + w) * 4) * 512 + (size_t)lane * 8;
#pragma unroll
      for (int nj = 0; nj < 4; ++nj) {
        bh[nj] = *(const short8*)(Bfh + fb + nj * 512);
        bl[nj] = *(const short8*)(Bfl + fb + nj * 512);
      }
    }
    __syncthreads();

    short8 ah[4], al[4];
#pragma unroll
    for (int mi = 0; mi < 4; ++mi) {
      int row = mi * 16 + lm;
      ah[mi] = *(const short8*)&As_hi[row][lkg * 8];
      al[mi] = *(const short8*)&As_lo[row][lkg * 8];
    }
#pragma unroll
    for (int mi = 0; mi < 4; ++mi)
#pragma unroll
      for (int nj = 0; nj < 4; ++nj) {
        acc[mi][nj] = __builtin_amdgcn_mfma_f32_16x16x32_bf16(ah[mi], bh[nj], acc[mi][nj], 0, 0, 0);
        acc[mi][nj] = __builtin_amdgcn_mfma_f32_16x16x32_bf16(ah[mi], bl[nj], acc[mi][nj], 0, 0, 0);
        acc[mi][nj] = __builtin_amdgcn_mfma_f32_16x16x32_bf16(al[mi], bh[nj], acc[mi][nj], 0, 0, 0);
      }
  }

  // epilogue: bf16 C (head-major) + exact alpha projections
  float a_sv[4], a_dv[4];
#pragma unroll
  for (int nj = 0; nj < 4; ++nj) {
    a_sv[nj] = avec[hb * 128 + nj * 16 + lm];
    a_dv[nj] = avec[hb * 128 + 64 + nj * 16 + lm];
  }
#pragma unroll
  for (int mi = 0; mi < 4; ++mi) {
#pragma unroll
    for (int rr = 0; rr < 4; ++rr) {
      int gm = m0 + mi * 16 + lkg * 4 + rr;
      float ps = acc[mi][0][rr] * a_sv[0] + acc[mi][1][rr] * a_sv[1] +
                 acc[mi][2][rr] * a_sv[2] + acc[mi][3][rr] * a_sv[3];
      float pd = acc[mi][0][rr] * a_dv[0] + acc[mi][1][rr] * a_dv[1] +
                 acc[mi][2][rr] * a_dv[2] + acc[mi][3][rr] * a_dv[3];
#pragma unroll
      for (int off = 1; off < 16; off <<= 1) {
        ps += __shfl_xor(ps, off, 16);
        pd += __shfl_xor(pd, off, 16);
      }
      if (gm < NND) {
#pragma unroll
        for (int nj = 0; nj < 4; ++nj)
          C[((size_t)hb * NND + gm) * 64 + nj * 16 + lm] = f32_to_bf16_rn(acc[mi][nj][rr]);
        if (lm == 0) {
          as_[(size_t)gm * 8 + hb] = ps;
          ad_[(size_t)gm * 8 + hb] = pd;
        }
      }
    }
  }
}

// ---------------- layer-2 GEMM: BM=64 (4 waves x 16 rows), BN=64 ------------
__global__ __launch_bounds__(256) void k_gemm2(
    const u16* __restrict__ Ahi_s, const u16* __restrict__ Alo_s,
    const u16* __restrict__ Bhi, const u16* __restrict__ Blo,
    u16* __restrict__ C_s,
    const float* __restrict__ avec,
    float* __restrict__ as_g, float* __restrict__ ad_g,
    int base_b, int zsh) {
  __shared__ u16 As_hi[64][40];
  __shared__ u16 As_lo[64][40];
  __shared__ u16 Bs_hi[64][40];
  __shared__ u16 Bs_lo[64][40];

  const int zmask = (1 << zsh) - 1;
  const int z = blockIdx.x & zmask;
  const int wg = blockIdx.x >> zsh;        // 0..156
  const int b = base_b + z;
  const u16* Ahi = Ahi_s + (size_t)z * ZSTRU;
  const u16* Alo = Alo_s + (size_t)z * ZSTRU;
  u16* C = C_s + (size_t)z * ZSTRU;
  float* as_ = as_g + (size_t)b * NND;
  float* ad_ = ad_g + (size_t)b * NND;

  const int tid = threadIdx.x;
  const int lane = tid & 63;
  const int w = tid >> 6;
  const int lm = lane & 15;
  const int lkg = lane >> 4;
  const int m0 = wg * 64;

  f32x4 acc[4];
#pragma unroll
  for (int j = 0; j < 4; ++j) acc[j] = 0.f;

  for (int kk = 0; kk < F1; kk += 32) {
    __syncthreads();
    // stage A: 64 rows x 32 u16 = 512 ushort4 units per buffer
#pragma unroll
    for (int u = 0; u < 2; ++u) {
      int e = u * 256 + tid;
      int rr = e >> 3, kf = (e & 7) * 4;
      int gm = m0 + rr;
      ushort4 hv = make_ushort4(0, 0, 0, 0), lv = make_ushort4(0, 0, 0, 0);
      if (gm < NND) {
        size_t g = (size_t)gm * F1 + kk + kf;
        hv = *(const ushort4*)(Ahi + g);
        lv = *(const ushort4*)(Alo + g);
      }
      *(ushort4*)&As_hi[rr][kf] = hv;
      *(ushort4*)&As_lo[rr][kf] = lv;
    }
    // stage B: 64 rows x 32 u16 = 512 ushort4 units per buffer (2 passes)
#pragma unroll
    for (int u = 0; u < 2; ++u) {
      int e = u * 256 + tid;
      int n = e >> 3, kf = (e & 7) * 4;
      size_t g = (size_t)n * F1 + kk + kf;
      *(ushort4*)&Bs_hi[n][kf] = *(const ushort4*)(Bhi + g);
      *(ushort4*)&Bs_lo[n][kf] = *(const ushort4*)(Blo + g);
    }
    __syncthreads();

    short8 ah, al, bh[4], bl[4];
    {
      int row = w * 16 + lm;
      ah = *(const short8*)&As_hi[row][lkg * 8];
      al = *(const short8*)&As_lo[row][lkg * 8];
    }
#pragma unroll
    for (int nj = 0; nj < 4; ++nj) {
      int row = nj * 16 + lm;
      bh[nj] = *(const short8*)&Bs_hi[row][lkg * 8];
      bl[nj] = *(const short8*)&Bs_lo[row][lkg * 8];
    }
#pragma unroll
    for (int nj = 0; nj < 4; ++nj) {
      acc[nj] = __builtin_amdgcn_mfma_f32_16x16x32_bf16(ah, bh[nj], acc[nj], 0, 0, 0);
      acc[nj] = __builtin_amdgcn_mfma_f32_16x16x32_bf16(ah, bl[nj], acc[nj], 0, 0, 0);
      acc[nj] = __builtin_amdgcn_mfma_f32_16x16x32_bf16(al, bh[nj], acc[nj], 0, 0, 0);
    }
  }

  float a_sv[4], a_dv[4];
#pragma unroll
  for (int nj = 0; nj < 4; ++nj) {
    a_sv[nj] = avec[nj * 16 + lm];
    a_dv[nj] = avec[64 + nj * 16 + lm];
  }
#pragma unroll
  for (int rr = 0; rr < 4; ++rr) {
    int gm = m0 + w * 16 + lkg * 4 + rr;
    float ps = acc[0][rr] * a_sv[0] + acc[1][rr] * a_sv[1] +
               acc[2][rr] * a_sv[2] + acc[3][rr] * a_sv[3];
    float pd = acc[0][rr] * a_dv[0] + acc[1][rr] * a_dv[1] +
               acc[2][rr] * a_dv[2] + acc[3][rr] * a_dv[3];
#pragma unroll
    for (int off = 1; off < 16; off <<= 1) {
      ps += __shfl_xor(ps, off, 16);
      pd += __shfl_xor(pd, off, 16);
    }
    if (gm < NND) {
#pragma unroll
      for (int nj = 0; nj < 4; ++nj)
        C[(size_t)gm * NCLS + nj * 16 + lm] = f32_to_bf16_rn(acc[nj][rr]);
      if (lm == 0) {
        as_[gm] = ps;
        ad_[gm] = pd;
      }
    }
  }
}

// ---- counting sort: hist -> scan -> LDS-binned coarse scatter -> fine ----

__global__ __launch_bounds__(256) void k_hist(const int* __restrict__ ei,
                                              int* __restrict__ counts) {
  int b = blockIdx.y;
  int e4 = (blockIdx.x * 256 + threadIdx.x) * 4;
  if (e4 < NED) {
    int4 s = *(const int4*)(ei + (size_t)b * 2 * NED + e4);
    atomicAdd(&counts[b * NND + s.x], 1);
    atomicAdd(&counts[b * NND + s.y], 1);
    atomicAdd(&counts[b * NND + s.z], 1);
    atomicAdd(&counts[b * NND + s.w], 1);
  }
}

// seq-10-per-thread + one 1024-wide LDS scan; one block per batch
__global__ __launch_bounds__(1024) void k_scan(const int* __restrict__ counts,
                                               int* __restrict__ rows) {
  __shared__ int lds[1024];
  const int b = blockIdx.x;
  const int tid = threadIdx.x;
  const int* cb = counts + b * NND;
  int* rb = rows + b * (NND + 1);
  int v[10];
  int s = 0;
  int base = tid * 10;
#pragma unroll
  for (int j = 0; j < 10; ++j) {
    int i = base + j;
    v[j] = (i < NND) ? cb[i] : 0;
    s += v[j];
  }
  lds[tid] = s;
  __syncthreads();
  for (int off = 1; off < 1024; off <<= 1) {
    int t = (tid >= off) ? lds[tid - off] : 0;
    __syncthreads();
    lds[tid] += t;
    __syncthreads();
  }
  int run = lds[tid] - s;
#pragma unroll
  for (int j = 0; j < 10; ++j) {
    int i = base + j;
    if (i < NND) rb[i] = run;
    run += v[j];
  }
  if (tid == 1023) rb[NND] = run;
}

// coarse: LDS-binned bucket scatter, dense per-(block,bucket) burst writes
__global__ __launch_bounds__(256) void k_scat_a(const int* __restrict__ ei,
                                                const int* __restrict__ rows,
                                                int* __restrict__ bcur,
                                                unsigned* __restrict__ tmp) {
  __shared__ unsigned stage[CHUNK];
  __shared__ int cnt[NBUCK], off[NBUCK], cur[NBUCK], gb[NBUCK];
  const int b = blockIdx.y;
  const int e0 = blockIdx.x * CHUNK;
  const int nE = min(CHUNK, NED - e0);
  const int tid = threadIdx.x;
  const int* sb = ei + (size_t)b * 2 * NED;
  const int* db = sb + NED;

  for (int k = tid; k < NBUCK; k += 256) cnt[k] = 0;
  __syncthreads();
  for (int j = tid; j < nE; j += 256)
    atomicAdd(&cnt[sb[e0 + j] >> NSH], 1);
  __syncthreads();
  if (tid == 0) {
    int run = 0;
    for (int k = 0; k < NBUCK; ++k) { off[k] = run; run += cnt[k]; }
  }
  __syncthreads();
  for (int k = tid; k < NBUCK; k += 256) cur[k] = off[k];
  __syncthreads();
  for (int j = tid; j < nE; j += 256) {
    int s = sb[e0 + j], d = db[e0 + j];
    int p = atomicAdd(&cur[s >> NSH], 1);
    stage[p] = ((unsigned)s << 16) | (unsigned)d;
  }
  __syncthreads();
  for (int k = tid; k < NBUCK; k += 256) {
    int c = cnt[k];
    gb[k] = c ? rows[b * (NND + 1) + (k << NSH)] + atomicAdd(&bcur[b * NBUCK + k], c)
              : 0;
  }
  __syncthreads();
  for (int i = tid; i < nE; i += 256) {
    unsigned p = stage[i];
    int k = (int)(p >> 16) >> NSH;
    tmp[(size_t)b * NED + gb[k] + (i - off[k])] = p;
  }
}

// fine: one block per bucket; LDS node cursors; writes in ~16KB window
__global__ __launch_bounds__(256) void k_scat_b(const int* __restrict__ rows,
                                                const unsigned* __restrict__ tmp,
                                                u16* __restrict__ dst_s) {
  __shared__ int cur[256];
  const int k = blockIdx.x, b = blockIdx.y;
  const int* rb = rows + b * (NND + 1);
  const int n0 = k << NSH;
  const int tid = threadIdx.x;
  cur[tid] = rb[min(n0 + tid, NND)];
  __syncthreads();
  const int beg = rb[n0];
  const int end = rb[min(n0 + 256, NND)];
  for (int i = beg + tid; i < end; i += 256) {
    unsigned p = tmp[(size_t)b * NED + i];
    int pos = atomicAdd(&cur[(int)(p >> 16) - n0], 1);
    dst_s[(size_t)b * NED + pos] = (u16)(p & 0xffffu);
  }
}

#define LKY(t) ((t) >= 0.f ? (t) : ALPHA_SLOPE * (t))

// layer-1 CSR agg: one wave per (head, node); lane = feature; head-outer grid
// so one 1.28MB head plane is L2-hot at a time. Fused score + elu + split.
__global__ __launch_bounds__(256) void k_agg1(
    const int* __restrict__ rows_g, const u16* __restrict__ dst_g,
    const u16* __restrict__ h1_s,
    const float* __restrict__ as_g, const float* __restrict__ ad_g,
    u16* __restrict__ xchi_s, u16* __restrict__ xclo_s,
    int base_b, int zsh) {
  const int zmask = (1 << zsh) - 1;
  const int z = blockIdx.x & zmask;
  const int idx = blockIdx.x >> zsh;       // 0..HEADS*2500-1, head-outer
  const int h = idx / 2500;
  const int nb = idx - h * 2500;
  const int b = base_b + z;
  const int* rows = rows_g + (size_t)b * (NND + 1);
  const u16* dst = dst_g + (size_t)b * NED;
  const u16* h1 = h1_s + (size_t)z * ZSTRU + (size_t)h * NND * 64;
  const float* as_ = as_g + (size_t)b * NND * 8;
  const float* ad_ = ad_g + (size_t)b * NND * 8;
  u16* xh = xchi_s + (size_t)z * ZSTRU;
  u16* xl = xclo_s + (size_t)z * ZSTRU;

  const int lane = threadIdx.x & 63;
  const int n = nb * 4 + (threadIdx.x >> 6);
  const float asv = as_[n * 8 + h];
  int beg = rows[n], end = rows[n + 1];
  float acc = 0.f, den = 0.f;
  int i = beg;
  for (; i + 4 <= end; i += 4) {
    int d0 = dst[i], d1 = dst[i + 1], d2 = dst[i + 2], d3 = dst[i + 3];
    float t0 = LKY(asv + ad_[d0 * 8 + h]);
    float t1 = LKY(asv + ad_[d1 * 8 + h]);
    float t2 = LKY(asv + ad_[d2 * 8 + h]);
    float t3 = LKY(asv + ad_[d3 * 8 + h]);
    float e0 = __expf(-t0), e1 = __expf(-t1);
    float e2 = __expf(-t2), e3 = __expf(-t3);
    float h0 = bf16_to_f32(h1[(size_t)d0 * 64 + lane]);
    float h1v = bf16_to_f32(h1[(size_t)d1 * 64 + lane]);
    float h2v = bf16_to_f32(h1[(size_t)d2 * 64 + lane]);
    float h3v = bf16_to_f32(h1[(size_t)d3 * 64 + lane]);
    acc = fmaf(e0, h0, acc); acc = fmaf(e1, h1v, acc);
    acc = fmaf(e2, h2v, acc); acc = fmaf(e3, h3v, acc);
    den += (e0 + e1) + (e2 + e3);
  }
  for (; i < end; ++i) {
    int d0 = dst[i];
    float t0 = LKY(asv + ad_[d0 * 8 + h]);
    float e0 = __expf(-t0);
    acc = fmaf(e0, bf16_to_f32(h1[(size_t)d0 * 64 + lane]), acc);
    den += e0;
  }
  float v = acc / (den + EPS);
  v = v > 0.f ? v : expm1f(v);
  u16 hh, ll; split1(v, hh, ll);
  size_t wo = (size_t)n * F1 + h * 64 + lane;
  xh[wo] = hh;
  xl[wo] = ll;
}

// layer-2 CSR agg, fused score + leaky output. one wave/node, lane=feature.
__global__ __launch_bounds__(256) void k_agg2(
    const int* __restrict__ rows_g, const u16* __restrict__ dst_g,
    const u16* __restrict__ h2_s,
    const float* __restrict__ as_g, const float* __restrict__ ad_g,
    float* __restrict__ out, int base_b, int zsh) {
  const int zmask = (1 << zsh) - 1;
  const int z = blockIdx.x & zmask;
  const int idx = blockIdx.x >> zsh;
  const int b = base_b + z;
  const int* rows = rows_g + (size_t)b * (NND + 1);
  const u16* dst = dst_g + (size_t)b * NED;
  const u16* h2 = h2_s + (size_t)z * ZSTRU;
  const float* as_ = as_g + (size_t)b * NND;
  const float* ad_ = ad_g + (size_t)b * NND;
  float* ob = out + (size_t)b * NND * NCLS;

  int lane = threadIdx.x & 63;
  int n = (idx * 256 + threadIdx.x) >> 6;
  if (n >= NND) return;
  const float asv = as_[n];
  int beg = rows[n], end = rows[n + 1];
  float acc = 0.f, den = 0.f;
  int i = beg;
  for (; i + 4 <= end; i += 4) {
    int d0 = dst[i], d1 = dst[i + 1], d2 = dst[i + 2], d3 = dst[i + 3];
    float t0 = LKY(asv + ad_[d0]);
    float t1 = LKY(asv + ad_[d1]);
    float t2 = LKY(asv + ad_[d2]);
    float t3 = LKY(asv + ad_[d3]);
    float e0 = __expf(-t0), e1 = __expf(-t1);
    float e2 = __expf(-t2), e3 = __expf(-t3);
    float h0 = bf16_to_f32(h2[(size_t)d0 * NCLS + lane]);
    float h1v = bf16_to_f32(h2[(size_t)d1 * NCLS + lane]);
    float h2v = bf16_to_f32(h2[(size_t)d2 * NCLS + lane]);
    float h3v = bf16_to_f32(h2[(size_t)d3 * NCLS + lane]);
    acc = fmaf(e0, h0, acc); acc = fmaf(e1, h1v, acc);
    acc = fmaf(e2, h2v, acc); acc = fmaf(e3, h3v, acc);
    den += (e0 + e1) + (e2 + e3);
  }
  for (; i < end; ++i) {
    int d0 = dst[i];
    float t0 = LKY(asv + ad_[d0]);
    float e0 = __expf(-t0);
    acc = fmaf(e0, bf16_to_f32(h2[(size_t)d0 * NCLS + lane]), acc);
    den += e0;
  }
  float v = acc / (den + EPS);
  ob[(size_t)n * NCLS + lane] = v >= 0.f ? v : OUT_SLOPE * v;
}

// ---------------- launcher ----------------
extern "C" void kernel_launch(void* const* d_in, const int* in_sizes, int n_in,
                              void* d_out, int out_size, void* d_ws, size_t ws_size,
                              hipStream_t stream) {
  const float* x       = (const float*)d_in[0];   // [B,N,256]
  const int*   ei      = (const int*)d_in[1];     // [B,2,E]
  const float* W_heads = (const float*)d_in[2];   // [8,256,64]
  const float* a_heads = (const float*)d_in[3];   // [8,128]
  const float* W_out   = (const float*)d_in[4];   // [512,64]
  const float* a_out   = (const float*)d_in[5];   // [128]
  float* out = (float*)d_out;

  char* base = (char*)d_ws;
  u16* wchi = (u16*)(base + B_WCHI);
  u16* wclo = (u16*)(base + B_WCLO);
  u16* wohi = (u16*)(base + B_WOHI);
  u16* wolo = (u16*)(base + B_WOLO);
  float* as1 = (float*)(base + B_AS1);
  float* ad1 = (float*)(base + B_AD1);
  float* as2 = (float*)(base + B_AS2);
  float* ad2 = (float*)(base + B_AD2);
  int* counts    = (int*)(base + B_CNT);
  int* bcur      = (int*)(base + B_BCUR);
  int* rows      = (int*)(base + B_ROWS);
  unsigned* tmp  = (unsigned*)(base + B_TMP);
  u16* dst_s     = (u16*)(base + B_DST);
  u16* scr       = (u16*)(base + B_SCR);

  int Z = 1, zsh = 0;
  if (ws_size >= B_SCR + 8 * S_PERZ) { Z = 8; zsh = 3; }
  else if (ws_size >= B_SCR + 4 * S_PERZ) { Z = 4; zsh = 2; }
  else if (ws_size >= B_SCR + 2 * S_PERZ) { Z = 2; zsh = 1; }

  u16* xchi = scr + 0;
  u16* xclo = scr + 5120000;
  u16* h1   = scr + 10240000;
  u16* h2   = scr + 15360000;

  // weight prep (once per call)
  k_wsplit1<<<64, 256, 0, stream>>>(W_heads, wchi, wclo);
  k_wsplit2<<<(NCLS * F1) / 256, 256, 0, stream>>>(W_out, wohi, wolo);

  // ---- counting sort for all batches ----
  hipMemsetAsync(counts, 0, B_ROWS - B_CNT, stream);   // counts + bcur
  k_hist<<<dim3((NED / 4 + 255) / 256, NB), 256, 0, stream>>>(ei, counts);
  k_scan<<<NB, 1024, 0, stream>>>(counts, rows);
  k_scat_a<<<dim3((NED + CHUNK - 1) / CHUNK, NB), 256, 0, stream>>>(ei, rows, bcur, tmp);
  k_scat_b<<<dim3(NBUCK, NB), 256, 0, stream>>>(rows, tmp, dst_s);

  const int nwg1 = ((NND + 63) / 64) * 2;   // 314
  const int nwg2 = (NND + 63) / 64;         // 157
  for (int bb = 0; bb < NB; bb += Z) {
    k_gemm1<<<dim3(nwg1 << zsh), 256, 0, stream>>>(
        x, wchi, wclo, h1, a_heads, as1, ad1, bb, zsh);
    k_agg1<<<dim3((HEADS * 2500) << zsh), 256, 0, stream>>>(
        rows, dst_s, h1, as1, ad1, xchi, xclo, bb, zsh);
    k_gemm2<<<dim3(nwg2 << zsh), 256, 0, stream>>>(
        xchi, xclo, wohi, wolo, h2, a_out, as2, ad2, bb, zsh);
    k_agg2<<<dim3(2500 << zsh), 256, 0, stream>>>(rows, dst_s, h2, as2, ad2,
                                                  out, bb, zsh);
  }
  (void)in_sizes; (void)n_in; (void)out_size;
}

// Round 12
// 453.998 us; speedup vs baseline: 1.4651x; 1.4651x over previous
//
#include <hip/hip_runtime.h>
#include <cstdint>
#include <cstddef>

// Problem shape (fixed by setup_inputs)
#define NND   10000     // nodes per graph
#define NED   160000    // edges per graph
#define NB    8         // batch
#define NF    256       // in features
#define NHID  64        // hidden per head
#define HEADS 8
#define F1    512       // HEADS*NHID
#define NCLS  64        // out classes

#define NSH   8         // bucket shift: 256 nodes per bucket
#define NBUCK 40        // ceil(NND/256)
#define CHUNK 4096      // edges per scat_a block

#define ALPHA_SLOPE 0.2f
#define OUT_SLOPE   0.01f
#define EPS         1e-16f

typedef unsigned short u16;
typedef short short8 __attribute__((ext_vector_type(8)));
typedef float f32x4 __attribute__((ext_vector_type(4)));

// ---------------- ws layout (byte offsets, 16B-aligned) ----------------
static const size_t B_WCHI = 0;                      // u16 frag-order [256 frag][64 lane][8]
static const size_t B_WCLO = 262144;
static const size_t B_WOHI = 524288;                 // u16 [64][512]
static const size_t B_WOLO = 589824;
static const size_t B_AS1  = 655360;                 // f32 [8][N][8]
static const size_t B_AD1  = 3215360;
static const size_t B_AS2  = 5775360;                // f32 [8][N]
static const size_t B_AD2  = 6095360;
static const size_t B_CNT  = 6415360;                // int [8][N]
static const size_t B_BCUR = 6735360;                // int [8][NBUCK] (pad to 4096)
static const size_t B_ROWS = 6739456;                // int [8][N+1]
static const size_t B_TMP  = 7059520;                // u32 [8][E] packed (s<<16|d)
static const size_t B_DST  = 12179520;               // u16 [8][E]
static const size_t B_SCR  = 14739520;               // Z slots
// per-z slot layout in u16 units (ZSTRU total):
//   off 0:          xchi [N][F1]
//   off 5,120,000:  xclo [N][F1]
//   off 10,240,000: h1   [N][F1]   (node-major)
//   off 15,360,000: h2   [N][NCLS]
#define ZSTRU 16000000ull
static const size_t S_PERZ = 2 * ZSTRU;              // bytes = 32,000,000

// ---------------- helpers ----------------
__device__ __forceinline__ u16 f32_to_bf16_rn(float f) {
  uint32_t u = __float_as_uint(f);
  uint32_t r = u + 0x7fffu + ((u >> 16) & 1u);
  return (u16)(r >> 16);
}
__device__ __forceinline__ float bf16_to_f32(u16 s) {
  return __uint_as_float((uint32_t)s << 16);
}
__device__ __forceinline__ void split1(float v, u16& h, u16& l) {
  h = f32_to_bf16_rn(v);
  float r = v - bf16_to_f32(h);
  l = f32_to_bf16_rn(r);
}

// ---------------- weight prep ----------------
// W_heads -> MFMA-fragment-order: frag = ((by*8 + ts)*4 + w)*4 + nj; per frag
// 64 lanes x 8 u16. Element (lane,j): n = by*256+w*64+nj*16+(lane&15),
// k = ts*32 + (lane>>4)*8 + j. One wave's fragment load = 1KB contiguous.
__global__ __launch_bounds__(256) void k_wsplit1(const float* __restrict__ Whd,
                                                 u16* __restrict__ hi,
                                                 u16* __restrict__ lo) {
  int t = blockIdx.x * 256 + threadIdx.x;   // 16384 threads
  int lane = t & 63;
  int frag = t >> 6;                        // 0..255
  int nj = frag & 3;
  int w  = (frag >> 2) & 3;
  int ts = (frag >> 4) & 7;
  int by = frag >> 7;
  int lm = lane & 15, lkg = lane >> 4;
  int n = by * 256 + w * 64 + nj * 16 + lm;
  int h = n >> 6, nc = n & 63;
  u16 hv[8], lv[8];
#pragma unroll
  for (int j = 0; j < 8; ++j) {
    int k = ts * 32 + lkg * 8 + j;
    split1(Whd[h * (NF * NHID) + k * NHID + nc], hv[j], lv[j]);
  }
  size_t o = (size_t)t * 8;
  *(ushort4*)(hi + o) = make_ushort4(hv[0], hv[1], hv[2], hv[3]);
  *(ushort4*)(hi + o + 4) = make_ushort4(hv[4], hv[5], hv[6], hv[7]);
  *(ushort4*)(lo + o) = make_ushort4(lv[0], lv[1], lv[2], lv[3]);
  *(ushort4*)(lo + o + 4) = make_ushort4(lv[4], lv[5], lv[6], lv[7]);
}
__global__ __launch_bounds__(256) void k_wsplit2(const float* __restrict__ Wo,
                                                 u16* __restrict__ hi,
                                                 u16* __restrict__ lo) {
  int idx = blockIdx.x * 256 + threadIdx.x;   // 64*512
  int n = idx >> 9, k = idx & 511;
  float v = Wo[k * NCLS + n];
  u16 h, l; split1(v, h, l);
  hi[idx] = h; lo[idx] = l;
}

// ---------------- layer-1 GEMM: BM=64, BN=256; A in LDS, B frags from L2 ----
// 1-D grid, z = blockIdx.x & (Z-1) -> batch z pinned to XCD z (when Z=8).
// Wave w owns cols [by*256 + w*64, +64) == head hb = by*4+w.
// h1 written NODE-MAJOR: C[gm][n0 + ...].
__global__ __launch_bounds__(256) void k_gemm1(
    const float* __restrict__ x,
    const u16* __restrict__ Bfh, const u16* __restrict__ Bfl,
    u16* __restrict__ h1_s,
    const float* __restrict__ avec,
    float* __restrict__ as_g, float* __restrict__ ad_g,
    int base_b, int zsh) {
  __shared__ u16 As_hi[64][40];
  __shared__ u16 As_lo[64][40];

  const int zmask = (1 << zsh) - 1;
  const int z = blockIdx.x & zmask;
  const int wg = blockIdx.x >> zsh;        // 0..313
  const int b = base_b + z;
  const float* A = x + (size_t)b * NND * NF;
  u16* C = h1_s + (size_t)z * ZSTRU;
  float* as_ = as_g + (size_t)b * NND * 8;
  float* ad_ = ad_g + (size_t)b * NND * 8;

  const int m0 = (wg >> 1) * 64;
  const int by = wg & 1;

  const int tid = threadIdx.x;
  const int lane = tid & 63;
  const int w = tid >> 6;
  const int lm = lane & 15;
  const int lkg = lane >> 4;
  const int hb = by * 4 + w;

  f32x4 acc[4][4];
#pragma unroll
  for (int mi = 0; mi < 4; ++mi)
#pragma unroll
    for (int nj = 0; nj < 4; ++nj) acc[mi][nj] = 0.f;

  for (int t = 0; t < 8; ++t) {
    const int kk = t * 32;
    __syncthreads();
    // stage A: 64 rows x 32 f32, fused split; 512 float4 units
#pragma unroll
    for (int u = 0; u < 2; ++u) {
      int e = u * 256 + tid;
      int rr = e >> 3, kf = (e & 7) * 4;
      int gm = m0 + rr;
      float4 v = make_float4(0.f, 0.f, 0.f, 0.f);
      if (gm < NND) v = *(const float4*)(A + (size_t)gm * NF + kk + kf);
      ushort4 hv, lv;
      split1(v.x, hv.x, lv.x); split1(v.y, hv.y, lv.y);
      split1(v.z, hv.z, lv.z); split1(v.w, hv.w, lv.w);
      *(ushort4*)&As_hi[rr][kf] = hv;
      *(ushort4*)&As_lo[rr][kf] = lv;
    }
    // B fragments straight from global (L2-hot, 1KB coalesced per load)
    short8 bh[4], bl[4];
    {
      size_t fb = (((size_t)(by * 8 + t) * 4 + w) * 4) * 512 + (size_t)lane * 8;
#pragma unroll
      for (int nj = 0; nj < 4; ++nj) {
        bh[nj] = *(const short8*)(Bfh + fb + nj * 512);
        bl[nj] = *(const short8*)(Bfl + fb + nj * 512);
      }
    }
    __syncthreads();

    short8 ah[4], al[4];
#pragma unroll
    for (int mi = 0; mi < 4; ++mi) {
      int row = mi * 16 + lm;
      ah[mi] = *(const short8*)&As_hi[row][lkg * 8];
      al[mi] = *(const short8*)&As_lo[row][lkg * 8];
    }
#pragma unroll
    for (int mi = 0; mi < 4; ++mi)
#pragma unroll
      for (int nj = 0; nj < 4; ++nj) {
        acc[mi][nj] = __builtin_amdgcn_mfma_f32_16x16x32_bf16(ah[mi], bh[nj], acc[mi][nj], 0, 0, 0);
        acc[mi][nj] = __builtin_amdgcn_mfma_f32_16x16x32_bf16(ah[mi], bl[nj], acc[mi][nj], 0, 0, 0);
        acc[mi][nj] = __builtin_amdgcn_mfma_f32_16x16x32_bf16(al[mi], bh[nj], acc[mi][nj], 0, 0, 0);
      }
  }

  // epilogue: bf16 C (node-major) + exact alpha projections
  float a_sv[4], a_dv[4];
#pragma unroll
  for (int nj = 0; nj < 4; ++nj) {
    a_sv[nj] = avec[hb * 128 + nj * 16 + lm];
    a_dv[nj] = avec[hb * 128 + 64 + nj * 16 + lm];
  }
  const int n0 = by * 256 + w * 64;
#pragma unroll
  for (int mi = 0; mi < 4; ++mi) {
#pragma unroll
    for (int rr = 0; rr < 4; ++rr) {
      int gm = m0 + mi * 16 + lkg * 4 + rr;
      float ps = acc[mi][0][rr] * a_sv[0] + acc[mi][1][rr] * a_sv[1] +
                 acc[mi][2][rr] * a_sv[2] + acc[mi][3][rr] * a_sv[3];
      float pd = acc[mi][0][rr] * a_dv[0] + acc[mi][1][rr] * a_dv[1] +
                 acc[mi][2][rr] * a_dv[2] + acc[mi][3][rr] * a_dv[3];
#pragma unroll
      for (int off = 1; off < 16; off <<= 1) {
        ps += __shfl_xor(ps, off, 16);
        pd += __shfl_xor(pd, off, 16);
      }
      if (gm < NND) {
#pragma unroll
        for (int nj = 0; nj < 4; ++nj)
          C[(size_t)gm * F1 + n0 + nj * 16 + lm] = f32_to_bf16_rn(acc[mi][nj][rr]);
        if (lm == 0) {
          as_[(size_t)gm * 8 + hb] = ps;
          ad_[(size_t)gm * 8 + hb] = pd;
        }
      }
    }
  }
}

// ---------------- layer-2 GEMM: BM=64 (4 waves x 16 rows), BN=64 ------------
__global__ __launch_bounds__(256) void k_gemm2(
    const u16* __restrict__ Ahi_s, const u16* __restrict__ Alo_s,
    const u16* __restrict__ Bhi, const u16* __restrict__ Blo,
    u16* __restrict__ C_s,
    const float* __restrict__ avec,
    float* __restrict__ as_g, float* __restrict__ ad_g,
    int base_b, int zsh) {
  __shared__ u16 As_hi[64][40];
  __shared__ u16 As_lo[64][40];
  __shared__ u16 Bs_hi[64][40];
  __shared__ u16 Bs_lo[64][40];

  const int zmask = (1 << zsh) - 1;
  const int z = blockIdx.x & zmask;
  const int wg = blockIdx.x >> zsh;        // 0..156
  const int b = base_b + z;
  const u16* Ahi = Ahi_s + (size_t)z * ZSTRU;
  const u16* Alo = Alo_s + (size_t)z * ZSTRU;
  u16* C = C_s + (size_t)z * ZSTRU;
  float* as_ = as_g + (size_t)b * NND;
  float* ad_ = ad_g + (size_t)b * NND;

  const int tid = threadIdx.x;
  const int lane = tid & 63;
  const int w = tid >> 6;
  const int lm = lane & 15;
  const int lkg = lane >> 4;
  const int m0 = wg * 64;

  f32x4 acc[4];
#pragma unroll
  for (int j = 0; j < 4; ++j) acc[j] = 0.f;

  for (int kk = 0; kk < F1; kk += 32) {
    __syncthreads();
    // stage A: 64 rows x 32 u16 = 512 ushort4 units per buffer
#pragma unroll
    for (int u = 0; u < 2; ++u) {
      int e = u * 256 + tid;
      int rr = e >> 3, kf = (e & 7) * 4;
      int gm = m0 + rr;
      ushort4 hv = make_ushort4(0, 0, 0, 0), lv = make_ushort4(0, 0, 0, 0);
      if (gm < NND) {
        size_t g = (size_t)gm * F1 + kk + kf;
        hv = *(const ushort4*)(Ahi + g);
        lv = *(const ushort4*)(Alo + g);
      }
      *(ushort4*)&As_hi[rr][kf] = hv;
      *(ushort4*)&As_lo[rr][kf] = lv;
    }
    // stage B: 64 rows x 32 u16 = 512 ushort4 units per buffer (2 passes)
#pragma unroll
    for (int u = 0; u < 2; ++u) {
      int e = u * 256 + tid;
      int n = e >> 3, kf = (e & 7) * 4;
      size_t g = (size_t)n * F1 + kk + kf;
      *(ushort4*)&Bs_hi[n][kf] = *(const ushort4*)(Bhi + g);
      *(ushort4*)&Bs_lo[n][kf] = *(const ushort4*)(Blo + g);
    }
    __syncthreads();

    short8 ah, al, bh[4], bl[4];
    {
      int row = w * 16 + lm;
      ah = *(const short8*)&As_hi[row][lkg * 8];
      al = *(const short8*)&As_lo[row][lkg * 8];
    }
#pragma unroll
    for (int nj = 0; nj < 4; ++nj) {
      int row = nj * 16 + lm;
      bh[nj] = *(const short8*)&Bs_hi[row][lkg * 8];
      bl[nj] = *(const short8*)&Bs_lo[row][lkg * 8];
    }
#pragma unroll
    for (int nj = 0; nj < 4; ++nj) {
      acc[nj] = __builtin_amdgcn_mfma_f32_16x16x32_bf16(ah, bh[nj], acc[nj], 0, 0, 0);
      acc[nj] = __builtin_amdgcn_mfma_f32_16x16x32_bf16(ah, bl[nj], acc[nj], 0, 0, 0);
      acc[nj] = __builtin_amdgcn_mfma_f32_16x16x32_bf16(al, bh[nj], acc[nj], 0, 0, 0);
    }
  }

  float a_sv[4], a_dv[4];
#pragma unroll
  for (int nj = 0; nj < 4; ++nj) {
    a_sv[nj] = avec[nj * 16 + lm];
    a_dv[nj] = avec[64 + nj * 16 + lm];
  }
#pragma unroll
  for (int rr = 0; rr < 4; ++rr) {
    int gm = m0 + w * 16 + lkg * 4 + rr;
    float ps = acc[0][rr] * a_sv[0] + acc[1][rr] * a_sv[1] +
               acc[2][rr] * a_sv[2] + acc[3][rr] * a_sv[3];
    float pd = acc[0][rr] * a_dv[0] + acc[1][rr] * a_dv[1] +
               acc[2][rr] * a_dv[2] + acc[3][rr] * a_dv[3];
#pragma unroll
    for (int off = 1; off < 16; off <<= 1) {
      ps += __shfl_xor(ps, off, 16);
      pd += __shfl_xor(pd, off, 16);
    }
    if (gm < NND) {
#pragma unroll
      for (int nj = 0; nj < 4; ++nj)
        C[(size_t)gm * NCLS + nj * 16 + lm] = f32_to_bf16_rn(acc[nj][rr]);
      if (lm == 0) {
        as_[gm] = ps;
        ad_[gm] = pd;
      }
    }
  }
}

// ---- counting sort: hist -> scan -> LDS-binned coarse scatter -> fine ----

__global__ __launch_bounds__(256) void k_hist(const int* __restrict__ ei,
                                              int* __restrict__ counts) {
  int b = blockIdx.y;
  int e4 = (blockIdx.x * 256 + threadIdx.x) * 4;
  if (e4 < NED) {
    int4 s = *(const int4*)(ei + (size_t)b * 2 * NED + e4);
    atomicAdd(&counts[b * NND + s.x], 1);
    atomicAdd(&counts[b * NND + s.y], 1);
    atomicAdd(&counts[b * NND + s.z], 1);
    atomicAdd(&counts[b * NND + s.w], 1);
  }
}

// seq-10-per-thread + one 1024-wide LDS scan; one block per batch
__global__ __launch_bounds__(1024) void k_scan(const int* __restrict__ counts,
                                               int* __restrict__ rows) {
  __shared__ int lds[1024];
  const int b = blockIdx.x;
  const int tid = threadIdx.x;
  const int* cb = counts + b * NND;
  int* rb = rows + b * (NND + 1);
  int v[10];
  int s = 0;
  int base = tid * 10;
#pragma unroll
  for (int j = 0; j < 10; ++j) {
    int i = base + j;
    v[j] = (i < NND) ? cb[i] : 0;
    s += v[j];
  }
  lds[tid] = s;
  __syncthreads();
  for (int off = 1; off < 1024; off <<= 1) {
    int t = (tid >= off) ? lds[tid - off] : 0;
    __syncthreads();
    lds[tid] += t;
    __syncthreads();
  }
  int run = lds[tid] - s;
#pragma unroll
  for (int j = 0; j < 10; ++j) {
    int i = base + j;
    if (i < NND) rb[i] = run;
    run += v[j];
  }
  if (tid == 1023) rb[NND] = run;
}

// coarse: LDS-binned bucket scatter, dense per-(block,bucket) burst writes
__global__ __launch_bounds__(256) void k_scat_a(const int* __restrict__ ei,
                                                const int* __restrict__ rows,
                                                int* __restrict__ bcur,
                                                unsigned* __restrict__ tmp) {
  __shared__ unsigned stage[CHUNK];
  __shared__ int cnt[NBUCK], off[NBUCK], cur[NBUCK], gb[NBUCK];
  const int b = blockIdx.y;
  const int e0 = blockIdx.x * CHUNK;
  const int nE = min(CHUNK, NED - e0);
  const int tid = threadIdx.x;
  const int* sb = ei + (size_t)b * 2 * NED;
  const int* db = sb + NED;

  for (int k = tid; k < NBUCK; k += 256) cnt[k] = 0;
  __syncthreads();
  for (int j = tid; j < nE; j += 256)
    atomicAdd(&cnt[sb[e0 + j] >> NSH], 1);
  __syncthreads();
  if (tid == 0) {
    int run = 0;
    for (int k = 0; k < NBUCK; ++k) { off[k] = run; run += cnt[k]; }
  }
  __syncthreads();
  for (int k = tid; k < NBUCK; k += 256) cur[k] = off[k];
  __syncthreads();
  for (int j = tid; j < nE; j += 256) {
    int s = sb[e0 + j], d = db[e0 + j];
    int p = atomicAdd(&cur[s >> NSH], 1);
    stage[p] = ((unsigned)s << 16) | (unsigned)d;
  }
  __syncthreads();
  for (int k = tid; k < NBUCK; k += 256) {
    int c = cnt[k];
    gb[k] = c ? rows[b * (NND + 1) + (k << NSH)] + atomicAdd(&bcur[b * NBUCK + k], c)
              : 0;
  }
  __syncthreads();
  for (int i = tid; i < nE; i += 256) {
    unsigned p = stage[i];
    int k = (int)(p >> 16) >> NSH;
    tmp[(size_t)b * NED + gb[k] + (i - off[k])] = p;
  }
}

// fine: one block per bucket; LDS node cursors; writes in ~16KB window
__global__ __launch_bounds__(256) void k_scat_b(const int* __restrict__ rows,
                                                const unsigned* __restrict__ tmp,
                                                u16* __restrict__ dst_s) {
  __shared__ int cur[256];
  const int k = blockIdx.x, b = blockIdx.y;
  const int* rb = rows + b * (NND + 1);
  const int n0 = k << NSH;
  const int tid = threadIdx.x;
  cur[tid] = rb[min(n0 + tid, NND)];
  __syncthreads();
  const int beg = rb[n0];
  const int end = rb[min(n0 + 256, NND)];
  for (int i = beg + tid; i < end; i += 256) {
    unsigned p = tmp[(size_t)b * NED + i];
    int pos = atomicAdd(&cur[(int)(p >> 16) - n0], 1);
    dst_s[(size_t)b * NED + pos] = (u16)(p & 0xffffu);
  }
}

#define UPK8(q, e) do { \
  acc[0] = fmaf(e, __uint_as_float((q).x << 16), acc[0]); \
  acc[1] = fmaf(e, __uint_as_float((q).x & 0xffff0000u), acc[1]); \
  acc[2] = fmaf(e, __uint_as_float((q).y << 16), acc[2]); \
  acc[3] = fmaf(e, __uint_as_float((q).y & 0xffff0000u), acc[3]); \
  acc[4] = fmaf(e, __uint_as_float((q).z << 16), acc[4]); \
  acc[5] = fmaf(e, __uint_as_float((q).z & 0xffff0000u), acc[5]); \
  acc[6] = fmaf(e, __uint_as_float((q).w << 16), acc[6]); \
  acc[7] = fmaf(e, __uint_as_float((q).w & 0xffff0000u), acc[7]); \
} while (0)

#define LKY(t) ((t) >= 0.f ? (t) : ALPHA_SLOPE * (t))

// layer-1 CSR agg, fused score + elu, writes split-bf16 xc. one wave/node.
// lane l owns features l*8..l*8+7 (16B of the bf16 h1 row), head = l>>3.
__global__ __launch_bounds__(256) void k_agg1(
    const int* __restrict__ rows_g, const u16* __restrict__ dst_g,
    const u16* __restrict__ h1_s,
    const float* __restrict__ as_g, const float* __restrict__ ad_g,
    u16* __restrict__ xchi_s, u16* __restrict__ xclo_s,
    int base_b, int zsh) {
  const int zmask = (1 << zsh) - 1;
  const int z = blockIdx.x & zmask;
  const int idx = blockIdx.x >> zsh;       // 0..2499
  const int b = base_b + z;
  const int* rows = rows_g + (size_t)b * (NND + 1);
  const u16* dst = dst_g + (size_t)b * NED;
  const u16* h1 = h1_s + (size_t)z * ZSTRU;
  const float* as_ = as_g + (size_t)b * NND * 8;
  const float* ad_ = ad_g + (size_t)b * NND * 8;
  u16* xh = xchi_s + (size_t)z * ZSTRU;
  u16* xl = xclo_s + (size_t)z * ZSTRU;

  int lane = threadIdx.x & 63;
  int n = (idx * 256 + threadIdx.x) >> 6;
  if (n >= NND) return;
  const int hh = lane >> 3;
  const float asv = as_[n * 8 + hh];
  int beg = rows[n], end = rows[n + 1];
  float acc[8] = {};
  float den = 0.f;
  int i = beg;
  for (; i + 4 <= end; i += 4) {
    int d0 = dst[i], d1 = dst[i + 1], d2 = dst[i + 2], d3 = dst[i + 3];
    float t0 = LKY(asv + ad_[d0 * 8 + hh]);
    float t1 = LKY(asv + ad_[d1 * 8 + hh]);
    float t2 = LKY(asv + ad_[d2 * 8 + hh]);
    float t3 = LKY(asv + ad_[d3 * 8 + hh]);
    float e0 = __expf(-t0), e1 = __expf(-t1);
    float e2 = __expf(-t2), e3 = __expf(-t3);
    uint4 q0 = *((const uint4*)(h1 + (size_t)d0 * F1) + lane);
    uint4 q1 = *((const uint4*)(h1 + (size_t)d1 * F1) + lane);
    uint4 q2 = *((const uint4*)(h1 + (size_t)d2 * F1) + lane);
    uint4 q3 = *((const uint4*)(h1 + (size_t)d3 * F1) + lane);
    UPK8(q0, e0); UPK8(q1, e1); UPK8(q2, e2); UPK8(q3, e3);
    den += (e0 + e1) + (e2 + e3);
  }
  for (; i < end; ++i) {
    int d0 = dst[i];
    float t0 = LKY(asv + ad_[d0 * 8 + hh]);
    float e0 = __expf(-t0);
    uint4 q0 = *((const uint4*)(h1 + (size_t)d0 * F1) + lane);
    UPK8(q0, e0);
    den += e0;
  }
  float inv = 1.f / (den + EPS);
  u16 oh[8], ol[8];
#pragma unroll
  for (int j = 0; j < 8; ++j) {
    float v = acc[j] * inv;
    v = v > 0.f ? v : expm1f(v);
    split1(v, oh[j], ol[j]);
  }
  size_t wo = (size_t)n * F1 + lane * 8;
  *(ushort4*)(xh + wo) = make_ushort4(oh[0], oh[1], oh[2], oh[3]);
  *(ushort4*)(xh + wo + 4) = make_ushort4(oh[4], oh[5], oh[6], oh[7]);
  *(ushort4*)(xl + wo) = make_ushort4(ol[0], ol[1], ol[2], ol[3]);
  *(ushort4*)(xl + wo + 4) = make_ushort4(ol[4], ol[5], ol[6], ol[7]);
}

// layer-2 CSR agg, fused score + leaky output. one wave/node, lane=feature.
__global__ __launch_bounds__(256) void k_agg2(
    const int* __restrict__ rows_g, const u16* __restrict__ dst_g,
    const u16* __restrict__ h2_s,
    const float* __restrict__ as_g, const float* __restrict__ ad_g,
    float* __restrict__ out, int base_b, int zsh) {
  const int zmask = (1 << zsh) - 1;
  const int z = blockIdx.x & zmask;
  const int idx = blockIdx.x >> zsh;
  const int b = base_b + z;
  const int* rows = rows_g + (size_t)b * (NND + 1);
  const u16* dst = dst_g + (size_t)b * NED;
  const u16* h2 = h2_s + (size_t)z * ZSTRU;
  const float* as_ = as_g + (size_t)b * NND;
  const float* ad_ = ad_g + (size_t)b * NND;
  float* ob = out + (size_t)b * NND * NCLS;

  int lane = threadIdx.x & 63;
  int n = (idx * 256 + threadIdx.x) >> 6;
  if (n >= NND) return;
  const float asv = as_[n];
  int beg = rows[n], end = rows[n + 1];
  float acc = 0.f, den = 0.f;
  int i = beg;
  for (; i + 4 <= end; i += 4) {
    int d0 = dst[i], d1 = dst[i + 1], d2 = dst[i + 2], d3 = dst[i + 3];
    float t0 = LKY(asv + ad_[d0]);
    float t1 = LKY(asv + ad_[d1]);
    float t2 = LKY(asv + ad_[d2]);
    float t3 = LKY(asv + ad_[d3]);
    float e0 = __expf(-t0), e1 = __expf(-t1);
    float e2 = __expf(-t2), e3 = __expf(-t3);
    float h0 = bf16_to_f32(h2[(size_t)d0 * NCLS + lane]);
    float h1v = bf16_to_f32(h2[(size_t)d1 * NCLS + lane]);
    float h2v = bf16_to_f32(h2[(size_t)d2 * NCLS + lane]);
    float h3v = bf16_to_f32(h2[(size_t)d3 * NCLS + lane]);
    acc = fmaf(e0, h0, acc); acc = fmaf(e1, h1v, acc);
    acc = fmaf(e2, h2v, acc); acc = fmaf(e3, h3v, acc);
    den += (e0 + e1) + (e2 + e3);
  }
  for (; i < end; ++i) {
    int d0 = dst[i];
    float t0 = LKY(asv + ad_[d0]);
    float e0 = __expf(-t0);
    acc = fmaf(e0, bf16_to_f32(h2[(size_t)d0 * NCLS + lane]), acc);
    den += e0;
  }
  float v = acc / (den + EPS);
  ob[(size_t)n * NCLS + lane] = v >= 0.f ? v : OUT_SLOPE * v;
}

// ---------------- launcher ----------------
extern "C" void kernel_launch(void* const* d_in, const int* in_sizes, int n_in,
                              void* d_out, int out_size, void* d_ws, size_t ws_size,
                              hipStream_t stream) {
  const float* x       = (const float*)d_in[0];   // [B,N,256]
  const int*   ei      = (const int*)d_in[1];     // [B,2,E]
  const float* W_heads = (const float*)d_in[2];   // [8,256,64]
  const float* a_heads = (const float*)d_in[3];   // [8,128]
  const float* W_out   = (const float*)d_in[4];   // [512,64]
  const float* a_out   = (const float*)d_in[5];   // [128]
  float* out = (float*)d_out;

  char* base = (char*)d_ws;
  u16* wchi = (u16*)(base + B_WCHI);
  u16* wclo = (u16*)(base + B_WCLO);
  u16* wohi = (u16*)(base + B_WOHI);
  u16* wolo = (u16*)(base + B_WOLO);
  float* as1 = (float*)(base + B_AS1);
  float* ad1 = (float*)(base + B_AD1);
  float* as2 = (float*)(base + B_AS2);
  float* ad2 = (float*)(base + B_AD2);
  int* counts    = (int*)(base + B_CNT);
  int* bcur      = (int*)(base + B_BCUR);
  int* rows      = (int*)(base + B_ROWS);
  unsigned* tmp  = (unsigned*)(base + B_TMP);
  u16* dst_s     = (u16*)(base + B_DST);
  u16* scr       = (u16*)(base + B_SCR);

  int Z = 1, zsh = 0;
  if (ws_size >= B_SCR + 8 * S_PERZ) { Z = 8; zsh = 3; }
  else if (ws_size >= B_SCR + 4 * S_PERZ) { Z = 4; zsh = 2; }
  else if (ws_size >= B_SCR + 2 * S_PERZ) { Z = 2; zsh = 1; }

  u16* xchi = scr + 0;
  u16* xclo = scr + 5120000;
  u16* h1   = scr + 10240000;
  u16* h2   = scr + 15360000;

  // weight prep (once per call)
  k_wsplit1<<<64, 256, 0, stream>>>(W_heads, wchi, wclo);
  k_wsplit2<<<(NCLS * F1) / 256, 256, 0, stream>>>(W_out, wohi, wolo);

  // ---- counting sort for all batches ----
  hipMemsetAsync(counts, 0, B_ROWS - B_CNT, stream);   // counts + bcur
  k_hist<<<dim3((NED / 4 + 255) / 256, NB), 256, 0, stream>>>(ei, counts);
  k_scan<<<NB, 1024, 0, stream>>>(counts, rows);
  k_scat_a<<<dim3((NED + CHUNK - 1) / CHUNK, NB), 256, 0, stream>>>(ei, rows, bcur, tmp);
  k_scat_b<<<dim3(NBUCK, NB), 256, 0, stream>>>(rows, tmp, dst_s);

  const int nwg1 = ((NND + 63) / 64) * 2;   // 314
  const int nwg2 = (NND + 63) / 64;         // 157
  for (int bb = 0; bb < NB; bb += Z) {
    k_gemm1<<<dim3(nwg1 << zsh), 256, 0, stream>>>(
        x, wchi, wclo, h1, a_heads, as1, ad1, bb, zsh);
    k_agg1<<<dim3(2500 << zsh), 256, 0, stream>>>(rows, dst_s, h1, as1, ad1,
                                                  xchi, xclo, bb, zsh);
    k_gemm2<<<dim3(nwg2 << zsh), 256, 0, stream>>>(
        xchi, xclo, wohi, wolo, h2, a_out, as2, ad2, bb, zsh);
    k_agg2<<<dim3(2500 << zsh), 256, 0, stream>>>(rows, dst_s, h2, as2, ad2,
                                                  out, bb, zsh);
  }
  (void)in_sizes; (void)n_in; (void)out_size;
}